// Round 2
// baseline (666.986 us; speedup 1.0000x reference)
//
#include <hip/hip_runtime.h>

#define N_USER 50000
#define N_ITEM 50000
#define N_NODE 50000
#define N_EDGE 1600000
#define D 64

#define NCAST 3125        // cast blocks per table: 50000*16/256 exactly
#define HCHUNK 8192       // edges per histogram block
#define NH ((N_EDGE + HCHUNK - 1) / HCHUNK)    // 196
#define SCHUNK 4096       // edges per scatter block
#define NSC ((N_EDGE + SCHUNK - 1) / SCHUNK)   // 391
#define SCAN_C 49         // 1024 * 49 = 50176 >= 50000

typedef __attribute__((ext_vector_type(8))) short short8;    // 8 bf16 = 4 VGPR
typedef __attribute__((ext_vector_type(4))) float floatx4;   // mfma acc

__device__ __forceinline__ unsigned short f32_to_bf16(float x) {
    unsigned u = __float_as_uint(x);
    unsigned r = (u + 0x7FFFu + ((u >> 16) & 1u)) >> 16;   // RNE
    return (unsigned short)r;
}
__device__ __forceinline__ float bf16_to_f32(unsigned short h) {
    return __uint_as_float(((unsigned)h) << 16);
}

// ---------------------------------------------------------------------------
// Kernel 1 (merged): blocks [0, 2*NH) build per-node in-degree histograms via
// fire-and-forget global atomics (3.2M/etype onto 50K counters = ~64/addr,
// well spread). Blocks [2*NH, ...) cast fp32->bf16 feature tables (BW-bound,
// overlaps under the atomic latency). No LDS, no bin array.
// ---------------------------------------------------------------------------
__global__ __launch_bounds__(256) void hist_cast(
    const float4* __restrict__ fU, ushort4* __restrict__ bU,
    const float4* __restrict__ fI, ushort4* __restrict__ bI,
    const int* __restrict__ dstA, int* __restrict__ cntI_,
    const int* __restrict__ dstB, int* __restrict__ cntU_)
{
    const int id = blockIdx.x;

    if (id >= 2 * NH) {
        // cast role: pure streaming, exact bounds (NCAST*256 == N_NODE*16)
        const int cid = id - 2 * NH;
        const int et = (cid >= NCAST) ? 1 : 0;
        const float4* __restrict__ in = et ? fI : fU;
        ushort4* __restrict__ out     = et ? bI : bU;
        int i = (cid - et * NCAST) * 256 + threadIdx.x;
        float4 v = in[i];
        ushort4 o;
        o.x = f32_to_bf16(v.x); o.y = f32_to_bf16(v.y);
        o.z = f32_to_bf16(v.z); o.w = f32_to_bf16(v.w);
        out[i] = o;
        return;
    }

    // histogram role
    const int et = (id >= NH) ? 1 : 0;
    const int* __restrict__ dst = et ? dstB : dstA;
    int* __restrict__ cnt       = et ? cntU_ : cntI_;
    const int base = (id - et * NH) * HCHUNK;
    const int n4 = (min(HCHUNK, N_EDGE - base)) >> 2;   // N_EDGE % 4 == 0
    const int4* dst4 = (const int4*)(dst + base);
    for (int i = threadIdx.x; i < n4; i += 256) {
        int4 d = dst4[i];
        atomicAdd(&cnt[d.x], 1);
        atomicAdd(&cnt[d.y], 1);
        atomicAdd(&cnt[d.z], 1);
        atomicAdd(&cnt[d.w], 1);
    }
}

// ---------------------------------------------------------------------------
// Kernel 2: exclusive scan of 50K counts per etype -> off (CSR offsets) and
// cur (scatter cursors). One 1024-thread block per etype; each thread owns a
// contiguous run of SCAN_C nodes (two passes over cnt; 2nd pass is L2-hot).
// ---------------------------------------------------------------------------
__global__ __launch_bounds__(1024) void scan_kernel(
    const int* __restrict__ cntI_, int* __restrict__ offI, int* __restrict__ curI,
    const int* __restrict__ cntU_, int* __restrict__ offU, int* __restrict__ curU)
{
    const int et = blockIdx.x;
    const int* __restrict__ cnt = et ? cntU_ : cntI_;
    int* __restrict__ off       = et ? offU : offI;
    int* __restrict__ cur       = et ? curU : curI;

    __shared__ int part[1024];
    const int t = threadIdx.x;
    const int base = t * SCAN_C;

    int sum = 0;
    for (int i = 0; i < SCAN_C; ++i) {
        int idx = base + i;
        sum += (idx < N_NODE) ? cnt[idx] : 0;
    }
    part[t] = sum;
    __syncthreads();

    // Hillis-Steele inclusive scan over the 1024 partials
    for (int o = 1; o < 1024; o <<= 1) {
        int v = (t >= o) ? part[t - o] : 0;
        __syncthreads();
        part[t] += v;
        __syncthreads();
    }

    int run = part[t] - sum;   // exclusive base for this thread's run
    for (int i = 0; i < SCAN_C; ++i) {
        int idx = base + i;
        if (idx < N_NODE) {
            off[idx] = run;
            cur[idx] = run;
            run += cnt[idx];
        }
    }
}

// ---------------------------------------------------------------------------
// Kernel 3: single-pass counting-sort scatter. pos = atomicAdd(cur[dst]);
// srt[pos] = u16 src. One scattered 2B store per edge (vs 4B bin store +
// 4B bin re-read + 2B srt store in the old bin+sort pipeline). The four
// atomics per iteration are independent -> overlap their L2 round-trips.
// ---------------------------------------------------------------------------
__global__ __launch_bounds__(256) void scatter_kernel(
    const int* __restrict__ srcA, const int* __restrict__ dstA,
    int* __restrict__ curI, unsigned short* __restrict__ srtI,
    const int* __restrict__ srcB, const int* __restrict__ dstB,
    int* __restrict__ curU, unsigned short* __restrict__ srtU)
{
    const int et = blockIdx.y;
    const int* __restrict__ src = et ? srcB : srcA;
    const int* __restrict__ dst = et ? dstB : dstA;
    int* __restrict__ cur       = et ? curU : curI;
    unsigned short* __restrict__ srt = et ? srtU : srtI;

    const int base = blockIdx.x * SCHUNK;
    const int n4 = (min(SCHUNK, N_EDGE - base)) >> 2;
    const int4* dst4 = (const int4*)(dst + base);
    const int4* src4 = (const int4*)(src + base);

    for (int i = threadIdx.x; i < n4; i += 256) {
        int4 d = dst4[i];
        int4 s = src4[i];
        int p0 = atomicAdd(&cur[d.x], 1);
        int p1 = atomicAdd(&cur[d.y], 1);
        int p2 = atomicAdd(&cur[d.z], 1);
        int p3 = atomicAdd(&cur[d.w], 1);
        srt[p0] = (unsigned short)s.x;
        srt[p1] = (unsigned short)s.y;
        srt[p2] = (unsigned short)s.z;
        srt[p3] = (unsigned short)s.w;
    }
}

// ---------------------------------------------------------------------------
// Kernel 4: raw-feature segment mean (bf16 gather). No LDS, 16 lanes/node,
// ushort4 per lane (128 B per edge), unroll-4 for memory-level parallelism.
// ---------------------------------------------------------------------------
__global__ __launch_bounds__(256) void aggregate_kernel(
    const ushort4* __restrict__ itemB,   // sources for user dst (rev)
    const ushort4* __restrict__ userB,   // sources for item dst (rate)
    const int* __restrict__ offU, const int* __restrict__ cntU, const unsigned short* __restrict__ srtU,
    const int* __restrict__ offI, const int* __restrict__ cntI, const unsigned short* __restrict__ srtI,
    ushort4* __restrict__ aggU, ushort4* __restrict__ aggI)
{
    int g = blockIdx.x * 16 + (threadIdx.x >> 4);
    if (g >= N_USER + N_ITEM) return;
    const int lane = threadIdx.x & 15;

    const bool isUser = (g < N_USER);
    const int d = isUser ? g : g - N_USER;
    const ushort4* __restrict__ tab = isUser ? itemB : userB;
    const int* __restrict__ off     = isUser ? offU : offI;
    const int* __restrict__ cntG    = isUser ? cntU : cntI;
    const unsigned short* __restrict__ srt = isUser ? srtU : srtI;
    ushort4* __restrict__ agg       = isUser ? aggU : aggI;

    const int start = off[d];
    const int c     = cntG[d];
    const int end   = start + c;

    float4 a0 = make_float4(0.f, 0.f, 0.f, 0.f);
    float4 a1 = make_float4(0.f, 0.f, 0.f, 0.f);
    float4 a2 = make_float4(0.f, 0.f, 0.f, 0.f);
    float4 a3 = make_float4(0.f, 0.f, 0.f, 0.f);
    int e = start;
    for (; e + 4 <= end; e += 4) {
        int s0 = (int)srt[e],     s1 = (int)srt[e + 1];
        int s2 = (int)srt[e + 2], s3 = (int)srt[e + 3];
        ushort4 w0 = tab[(size_t)s0 * 16 + lane];
        ushort4 w1 = tab[(size_t)s1 * 16 + lane];
        ushort4 w2 = tab[(size_t)s2 * 16 + lane];
        ushort4 w3 = tab[(size_t)s3 * 16 + lane];
        a0.x += bf16_to_f32(w0.x); a0.y += bf16_to_f32(w0.y);
        a0.z += bf16_to_f32(w0.z); a0.w += bf16_to_f32(w0.w);
        a1.x += bf16_to_f32(w1.x); a1.y += bf16_to_f32(w1.y);
        a1.z += bf16_to_f32(w1.z); a1.w += bf16_to_f32(w1.w);
        a2.x += bf16_to_f32(w2.x); a2.y += bf16_to_f32(w2.y);
        a2.z += bf16_to_f32(w2.z); a2.w += bf16_to_f32(w2.w);
        a3.x += bf16_to_f32(w3.x); a3.y += bf16_to_f32(w3.y);
        a3.z += bf16_to_f32(w3.z); a3.w += bf16_to_f32(w3.w);
    }
    for (; e < end; ++e) {
        int s0 = (int)srt[e];
        ushort4 w0 = tab[(size_t)s0 * 16 + lane];
        a0.x += bf16_to_f32(w0.x); a0.y += bf16_to_f32(w0.y);
        a0.z += bf16_to_f32(w0.z); a0.w += bf16_to_f32(w0.w);
    }
    a0.x += a1.x + a2.x + a3.x;
    a0.y += a1.y + a2.y + a3.y;
    a0.z += a1.z + a2.z + a3.z;
    a0.w += a1.w + a2.w + a3.w;

    const float inv = (c > 0) ? 1.0f / (float)c : 0.0f;
    ushort4 o;
    o.x = f32_to_bf16(a0.x * inv);
    o.y = f32_to_bf16(a0.y * inv);
    o.z = f32_to_bf16(a0.z * inv);
    o.w = f32_to_bf16(a0.w * inv);
    agg[(size_t)g * 16 + lane - (isUser ? 0 : (size_t)N_USER * 16)] = o;
}

// ---------------------------------------------------------------------------
// Kernel 5: final dual GEMM via MFMA (16x16x32 bf16). 64 rows/block, 4 waves.
// D = agg@W + feat@loop (+ biases in epilogue). Layouts guide-verified.
// ---------------------------------------------------------------------------
__global__ __launch_bounds__(256, 4) void final_gemm(
    const unsigned short* __restrict__ aggU_, const unsigned short* __restrict__ featU_,
    const int* __restrict__ cntU_, const float* __restrict__ WU,
    const float* __restrict__ beU,
    const unsigned short* __restrict__ aggI_, const unsigned short* __restrict__ featI_,
    const int* __restrict__ cntI_, const float* __restrict__ WI,
    const float* __restrict__ beI,
    const float* __restrict__ loop_w, const float* __restrict__ h_bias,
    float* __restrict__ out)
{
    const int et = blockIdx.y;
    const unsigned short* __restrict__ agg  = et ? aggI_ : aggU_;
    const unsigned short* __restrict__ feat = et ? featI_ : featU_;
    const int* __restrict__ cntG            = et ? cntI_ : cntU_;
    const float* __restrict__ W             = et ? WI : WU;
    const float* __restrict__ b_et          = et ? beI : beU;
    float* __restrict__ outN = out + (et ? (size_t)N_USER * D : 0);

    __shared__ unsigned short sWt[64][72];   // W^T bf16:   sWt[n][k]
    __shared__ unsigned short sLt[64][72];   // loop^T bf16
    __shared__ float sbe[64], sbh[64];
    __shared__ int sCnt[64];

    const int tid = threadIdx.x;
    const int row0 = blockIdx.x * 64;

    for (int i = tid; i < 4096; i += 256) {
        int k = i >> 6, n = i & 63;
        sWt[n][k] = f32_to_bf16(W[i]);        // W[k][n]
        sLt[n][k] = f32_to_bf16(loop_w[i]);
    }
    if (tid < 64) {
        sbe[tid] = b_et[tid];
        sbh[tid] = h_bias[tid];
        int r = row0 + tid;
        sCnt[tid] = (r < N_NODE) ? cntG[r] : 0;
    }
    __syncthreads();

    const int wave = tid >> 6;
    const int lane = tid & 63;
    const int quad = lane >> 4;
    const int l16  = lane & 15;

    const int rowA = row0 + wave * 16 + l16;
    const int rA = (rowA < N_NODE) ? rowA : (N_NODE - 1);
    short8 aAgg0  = *(const short8*)(agg  + (size_t)rA * 64 +      quad * 8);
    short8 aAgg1  = *(const short8*)(agg  + (size_t)rA * 64 + 32 + quad * 8);
    short8 aFeat0 = *(const short8*)(feat + (size_t)rA * 64 +      quad * 8);
    short8 aFeat1 = *(const short8*)(feat + (size_t)rA * 64 + 32 + quad * 8);

    floatx4 acc[4];
    #pragma unroll
    for (int t = 0; t < 4; ++t) {
        const int n = t * 16 + l16;
        short8 bW0 = *(const short8*)&sWt[n][     quad * 8];
        short8 bW1 = *(const short8*)&sWt[n][32 + quad * 8];
        short8 bL0 = *(const short8*)&sLt[n][     quad * 8];
        short8 bL1 = *(const short8*)&sLt[n][32 + quad * 8];
        floatx4 a = {0.f, 0.f, 0.f, 0.f};
        a = __builtin_amdgcn_mfma_f32_16x16x32_bf16(aAgg0,  bW0, a, 0, 0, 0);
        a = __builtin_amdgcn_mfma_f32_16x16x32_bf16(aAgg1,  bW1, a, 0, 0, 0);
        a = __builtin_amdgcn_mfma_f32_16x16x32_bf16(aFeat0, bL0, a, 0, 0, 0);
        a = __builtin_amdgcn_mfma_f32_16x16x32_bf16(aFeat1, bL1, a, 0, 0, 0);
        acc[t] = a;
    }

    #pragma unroll
    for (int t = 0; t < 4; ++t) {
        const int col = t * 16 + l16;
        const float bh = sbh[col], be = sbe[col];
        #pragma unroll
        for (int i = 0; i < 4; ++i) {
            int lrow = wave * 16 + quad * 4 + i;
            int r = row0 + lrow;
            if (r < N_NODE) {
                float v = acc[t][i] + bh + (sCnt[lrow] > 0 ? be : 0.f);
                outN[(size_t)r * D + col] = v;
            }
        }
    }
}

// ---------------------------------------------------------------------------
extern "C" void kernel_launch(void* const* d_in, const int* in_sizes, int n_in,
                              void* d_out, int out_size, void* d_ws, size_t ws_size,
                              hipStream_t stream)
{
    const float* user_feat = (const float*)d_in[0];
    const float* item_feat = (const float*)d_in[1];
    const int*   rate_src  = (const int*)d_in[2];
    const int*   rate_dst  = (const int*)d_in[3];
    const int*   rev_src   = (const int*)d_in[4];
    const int*   rev_dst   = (const int*)d_in[5];
    const float* W_rate    = (const float*)d_in[6];
    const float* b_rate    = (const float*)d_in[7];
    const float* W_rev     = (const float*)d_in[8];
    const float* b_rev     = (const float*)d_in[9];
    const float* loop_w    = (const float*)d_in[10];
    const float* h_bias    = (const float*)d_in[11];
    float* out = (float*)d_out;

    // workspace layout (~34 MB)
    char* p = (char*)d_ws;
    ushort4* userB = (ushort4*)p; p += (size_t)N_USER * D * 2;                 // 6.4 MB
    ushort4* itemB = (ushort4*)p; p += (size_t)N_ITEM * D * 2;                 // 6.4 MB
    unsigned short* srtI = (unsigned short*)p; p += (size_t)N_EDGE * 2;        // 3.2 MB
    unsigned short* srtU = (unsigned short*)p; p += (size_t)N_EDGE * 2;        // 3.2 MB
    ushort4* aggI  = (ushort4*)p; p += (size_t)N_NODE * D * 2;                 // 6.4 MB
    ushort4* aggU  = (ushort4*)p; p += (size_t)N_NODE * D * 2;                 // 6.4 MB
    int* cntI = (int*)p; p += (size_t)N_NODE * 4;   // keep cntI+cntU adjacent (one memset)
    int* cntU = (int*)p; p += (size_t)N_NODE * 4;
    int* offI = (int*)p; p += (size_t)N_NODE * 4;
    int* offU = (int*)p; p += (size_t)N_NODE * 4;
    int* curI = (int*)p; p += (size_t)N_NODE * 4;
    int* curU = (int*)p; p += (size_t)N_NODE * 4;
    (void)ws_size;

    // zero the in-degree counters (400 KB)
    hipMemsetAsync(cntI, 0, (size_t)2 * N_NODE * sizeof(int), stream);

    // 1) merged histogram (blocks [0, 2*NH), atomic-bound, dispatched first)
    //    + cast (blocks [2*NH, ...), BW-bound, overlaps)
    hist_cast<<<dim3(2 * NH + 2 * NCAST), 256, 0, stream>>>(
        (const float4*)user_feat, userB, (const float4*)item_feat, itemB,
        rate_dst, cntI,
        rev_dst,  cntU);

    // 2) exclusive scan -> off + cur (one block per etype)
    scan_kernel<<<dim3(2), 1024, 0, stream>>>(
        cntI, offI, curI,
        cntU, offU, curU);

    // 3) counting-sort scatter -> u16 srt
    scatter_kernel<<<dim3(NSC, 2), 256, 0, stream>>>(
        rate_src, rate_dst, curI, srtI,
        rev_src,  rev_dst,  curU, srtU);

    // 4) raw-feature segment mean (bf16, unroll-4)
    aggregate_kernel<<<(N_USER + N_ITEM + 15) / 16, 256, 0, stream>>>(
        itemB, userB,
        offU, cntU, srtU,
        offI, cntI, srtI,
        aggU, aggI);

    // 5) final dual GEMM via MFMA (merged, fully writes d_out)
    final_gemm<<<dim3((N_NODE + 63) / 64, 2), 256, 0, stream>>>(
        (const unsigned short*)aggU, (const unsigned short*)userB, cntU, W_rev, b_rev,
        (const unsigned short*)aggI, (const unsigned short*)itemB, cntI, W_rate, b_rate,
        loop_w, h_bias, out);

    (void)in_sizes; (void)n_in; (void)out_size;
}

// Round 3
// 208.832 us; speedup vs baseline: 3.1939x; 3.1939x over previous
//
#include <hip/hip_runtime.h>

#define N_USER 50000
#define N_ITEM 50000
#define N_NODE 50000
#define N_EDGE 1600000
#define D 64

#define CB_SHIFT 8        // 256 nodes per coarse bucket
#define NBKT 196          // 196*256 = 50176 >= 50000
#define BCAP 10240        // per-bucket capacity (mean 8192, sigma~90 -> 22 sigma)
#define CHUNK 8192        // edges per chunk-sort block
#define NCH ((N_EDGE + CHUNK - 1) / CHUNK)     // 196
#define NCAST 3125        // cast blocks per table: 50000*16/256 exactly

typedef __attribute__((ext_vector_type(8))) short short8;    // 8 bf16 = 4 VGPR
typedef __attribute__((ext_vector_type(4))) float floatx4;   // mfma acc

__device__ __forceinline__ unsigned short f32_to_bf16(float x) {
    unsigned u = __float_as_uint(x);
    unsigned r = (u + 0x7FFFu + ((u >> 16) & 1u)) >> 16;   // RNE
    return (unsigned short)r;
}
__device__ __forceinline__ float bf16_to_f32(unsigned short h) {
    return __uint_as_float(((unsigned)h) << 16);
}

// ---------------------------------------------------------------------------
// Kernel 1 (merged): blocks [0, 2*NCH) chunk-sort 8192 edges each into coarse
// dst-buckets ENTIRELY IN LDS, then copy per-bucket segments (~42 entries,
// 168 B) to reserved contiguous windows in gbin. Every global write is a
// coalesced segment copy -- no per-edge scattered stores (round-2 lesson:
// scattered small stores cost a full 64B line writeback each).
// Blocks [2*NCH, ...) cast fp32->bf16 feature tables (BW-bound, overlaps).
// ---------------------------------------------------------------------------
__global__ __launch_bounds__(256) void cast_bin(
    const float4* __restrict__ fU, ushort4* __restrict__ bU,
    const float4* __restrict__ fI, ushort4* __restrict__ bI,
    const int* __restrict__ srcA, const int* __restrict__ dstA, unsigned* __restrict__ gbinA,
    const int* __restrict__ srcB, const int* __restrict__ dstB, unsigned* __restrict__ gbinB,
    int* __restrict__ fcur)
{
    __shared__ unsigned lbin[CHUNK];   // 32 KB staging
    __shared__ int hist[NBKT];
    __shared__ int lofs[NBKT];
    __shared__ int lcur[NBKT];
    __shared__ int gbase[NBKT];
    __shared__ int sc[256];

    const int id = blockIdx.x;

    if (id >= 2 * NCH) {
        // cast role: pure streaming, exact bounds (NCAST*256 == N_NODE*16)
        const int cid = id - 2 * NCH;
        const int et = (cid >= NCAST) ? 1 : 0;
        const float4* __restrict__ in = et ? fI : fU;
        ushort4* __restrict__ out     = et ? bI : bU;
        int i = (cid - et * NCAST) * 256 + threadIdx.x;
        float4 v = in[i];
        ushort4 o;
        o.x = f32_to_bf16(v.x); o.y = f32_to_bf16(v.y);
        o.z = f32_to_bf16(v.z); o.w = f32_to_bf16(v.w);
        out[i] = o;
        return;
    }

    // chunk-sort role
    const int et = (id >= NCH) ? 1 : 0;
    const int chunk = id - et * NCH;
    const int* __restrict__ src = et ? srcB : srcA;
    const int* __restrict__ dst = et ? dstB : dstA;
    unsigned* __restrict__ gbin = et ? gbinB : gbinA;
    int* __restrict__ fc = fcur + et * NBKT;

    const int base = chunk * CHUNK;
    const int nE = min(CHUNK, N_EDGE - base);
    const int n4 = nE >> 2;                      // nE % 4 == 0 always here
    const int4* dst4 = (const int4*)(dst + base);
    const int4* src4 = (const int4*)(src + base);
    const int tid = threadIdx.x;

    for (int i = tid; i < NBKT; i += 256) hist[i] = 0;
    __syncthreads();

    // pass 1: count per coarse bucket
    for (int i = tid; i < n4; i += 256) {
        int4 d = dst4[i];
        atomicAdd(&hist[d.x >> CB_SHIFT], 1);
        atomicAdd(&hist[d.y >> CB_SHIFT], 1);
        atomicAdd(&hist[d.z >> CB_SHIFT], 1);
        atomicAdd(&hist[d.w >> CB_SHIFT], 1);
    }
    __syncthreads();

    // exclusive scan over 196 counts (256-wide Hillis-Steele)
    int v = (tid < NBKT) ? hist[tid] : 0;
    sc[tid] = v;
    __syncthreads();
    for (int o = 1; o < 256; o <<= 1) {
        int t = (tid >= o) ? sc[tid - o] : 0;
        __syncthreads();
        sc[tid] += t;
        __syncthreads();
    }
    if (tid < NBKT) {
        int excl = sc[tid] - v;
        lofs[tid] = excl;
        lcur[tid] = excl;
        // reserve contiguous global window for this chunk's segment
        gbase[tid] = v ? (tid * BCAP + atomicAdd(&fc[tid], v)) : 0;
    }
    __syncthreads();

    // pass 2: scatter packed (dst<<16)|src into LDS (re-read edges, L2-hot)
    for (int i = tid; i < n4; i += 256) {
        int4 d = dst4[i];
        int4 s = src4[i];
        { int p = atomicAdd(&lcur[d.x >> CB_SHIFT], 1); lbin[p] = ((unsigned)d.x << 16) | (unsigned)s.x; }
        { int p = atomicAdd(&lcur[d.y >> CB_SHIFT], 1); lbin[p] = ((unsigned)d.y << 16) | (unsigned)s.y; }
        { int p = atomicAdd(&lcur[d.z >> CB_SHIFT], 1); lbin[p] = ((unsigned)d.z << 16) | (unsigned)s.z; }
        { int p = atomicAdd(&lcur[d.w >> CB_SHIFT], 1); lbin[p] = ((unsigned)d.w << 16) | (unsigned)s.w; }
    }
    __syncthreads();

    // copy out: one wave per bucket segment, contiguous global writes
    const int wv = tid >> 6, ln = tid & 63;
    for (int b = wv; b < NBKT; b += 4) {
        const int s0 = lofs[b], c = hist[b], g = gbase[b];
        for (int t = ln; t < c; t += 64) gbin[g + t] = lbin[s0 + t];
    }
}

// ---------------------------------------------------------------------------
// Kernel 2: per-coarse-bucket counting sort -> u16 srt (LDS-staged, coalesced
// write-out) + per-node off/cnt. One block per (bucket, etype), ~8192 edges,
// window-contiguous global reads.
// ---------------------------------------------------------------------------
__global__ __launch_bounds__(256) void bucket_sort(
    const unsigned* __restrict__ gbinI, unsigned short* __restrict__ srtI,
    int* __restrict__ offI, int* __restrict__ cntI,
    const unsigned* __restrict__ gbinU, unsigned short* __restrict__ srtU,
    int* __restrict__ offU, int* __restrict__ cntU,
    const int* __restrict__ fcur)
{
    const int et = blockIdx.y;
    const unsigned* __restrict__ gbin = et ? gbinU : gbinI;
    unsigned short* __restrict__ srt  = et ? srtU : srtI;
    int* __restrict__ off   = et ? offU : offI;
    int* __restrict__ cntG  = et ? cntU : cntI;
    const int b = blockIdx.x;
    const int startg = b * BCAP;
    const int n = fcur[et * NBKT + b];
    const int nodebase = b << CB_SHIFT;
    const int tid = threadIdx.x;

    __shared__ int cnt[256];
    __shared__ int sc[256];
    __shared__ int pos[256];
    __shared__ unsigned short lsrt[BCAP];   // 20 KB staging

    cnt[tid] = 0;
    __syncthreads();

    for (int i = tid; i < n; i += 256)
        atomicAdd(&cnt[(int)(gbin[startg + i] >> 16) - nodebase], 1);
    __syncthreads();

    int v = cnt[tid];
    sc[tid] = v;
    __syncthreads();
    for (int o = 1; o < 256; o <<= 1) {
        int t = (tid >= o) ? sc[tid - o] : 0;
        __syncthreads();
        sc[tid] += t;
        __syncthreads();
    }
    {
        int excl = sc[tid] - v;
        pos[tid] = excl;
        int node = nodebase + tid;
        if (node < N_NODE) { off[node] = startg + excl; cntG[node] = v; }
    }
    __syncthreads();

    for (int i = tid; i < n; i += 256) {
        unsigned p = gbin[startg + i];                  // L2-hot re-read
        int q = atomicAdd(&pos[(int)(p >> 16) - nodebase], 1);
        lsrt[q] = (unsigned short)(p & 0xFFFFu);        // LDS scatter
    }
    __syncthreads();

    for (int i = tid; i < n; i += 256) srt[startg + i] = lsrt[i];   // coalesced
}

// ---------------------------------------------------------------------------
// Kernel 3: raw-feature segment mean (bf16 gather). No LDS, 16 lanes/node,
// ushort4 per lane (128 B per edge), unroll-4 for memory-level parallelism.
// ---------------------------------------------------------------------------
__global__ __launch_bounds__(256) void aggregate_kernel(
    const ushort4* __restrict__ itemB,   // sources for user dst (rev)
    const ushort4* __restrict__ userB,   // sources for item dst (rate)
    const int* __restrict__ offU, const int* __restrict__ cntU, const unsigned short* __restrict__ srtU,
    const int* __restrict__ offI, const int* __restrict__ cntI, const unsigned short* __restrict__ srtI,
    ushort4* __restrict__ aggU, ushort4* __restrict__ aggI)
{
    int g = blockIdx.x * 16 + (threadIdx.x >> 4);
    if (g >= N_USER + N_ITEM) return;
    const int lane = threadIdx.x & 15;

    const bool isUser = (g < N_USER);
    const int d = isUser ? g : g - N_USER;
    const ushort4* __restrict__ tab = isUser ? itemB : userB;
    const int* __restrict__ off     = isUser ? offU : offI;
    const int* __restrict__ cntG    = isUser ? cntU : cntI;
    const unsigned short* __restrict__ srt = isUser ? srtU : srtI;
    ushort4* __restrict__ agg       = isUser ? aggU : aggI;

    const int start = off[d];
    const int c     = cntG[d];
    const int end   = start + c;

    float4 a0 = make_float4(0.f, 0.f, 0.f, 0.f);
    float4 a1 = make_float4(0.f, 0.f, 0.f, 0.f);
    float4 a2 = make_float4(0.f, 0.f, 0.f, 0.f);
    float4 a3 = make_float4(0.f, 0.f, 0.f, 0.f);
    int e = start;
    for (; e + 4 <= end; e += 4) {
        int s0 = (int)srt[e],     s1 = (int)srt[e + 1];
        int s2 = (int)srt[e + 2], s3 = (int)srt[e + 3];
        ushort4 w0 = tab[(size_t)s0 * 16 + lane];
        ushort4 w1 = tab[(size_t)s1 * 16 + lane];
        ushort4 w2 = tab[(size_t)s2 * 16 + lane];
        ushort4 w3 = tab[(size_t)s3 * 16 + lane];
        a0.x += bf16_to_f32(w0.x); a0.y += bf16_to_f32(w0.y);
        a0.z += bf16_to_f32(w0.z); a0.w += bf16_to_f32(w0.w);
        a1.x += bf16_to_f32(w1.x); a1.y += bf16_to_f32(w1.y);
        a1.z += bf16_to_f32(w1.z); a1.w += bf16_to_f32(w1.w);
        a2.x += bf16_to_f32(w2.x); a2.y += bf16_to_f32(w2.y);
        a2.z += bf16_to_f32(w2.z); a2.w += bf16_to_f32(w2.w);
        a3.x += bf16_to_f32(w3.x); a3.y += bf16_to_f32(w3.y);
        a3.z += bf16_to_f32(w3.z); a3.w += bf16_to_f32(w3.w);
    }
    for (; e < end; ++e) {
        int s0 = (int)srt[e];
        ushort4 w0 = tab[(size_t)s0 * 16 + lane];
        a0.x += bf16_to_f32(w0.x); a0.y += bf16_to_f32(w0.y);
        a0.z += bf16_to_f32(w0.z); a0.w += bf16_to_f32(w0.w);
    }
    a0.x += a1.x + a2.x + a3.x;
    a0.y += a1.y + a2.y + a3.y;
    a0.z += a1.z + a2.z + a3.z;
    a0.w += a1.w + a2.w + a3.w;

    const float inv = (c > 0) ? 1.0f / (float)c : 0.0f;
    ushort4 o;
    o.x = f32_to_bf16(a0.x * inv);
    o.y = f32_to_bf16(a0.y * inv);
    o.z = f32_to_bf16(a0.z * inv);
    o.w = f32_to_bf16(a0.w * inv);
    agg[(size_t)g * 16 + lane - (isUser ? 0 : (size_t)N_USER * 16)] = o;
}

// ---------------------------------------------------------------------------
// Kernel 4: final dual GEMM via MFMA (16x16x32 bf16). 64 rows/block, 4 waves.
// D = agg@W + feat@loop (+ biases in epilogue). Layouts guide-verified.
// ---------------------------------------------------------------------------
__global__ __launch_bounds__(256, 4) void final_gemm(
    const unsigned short* __restrict__ aggU_, const unsigned short* __restrict__ featU_,
    const int* __restrict__ cntU_, const float* __restrict__ WU,
    const float* __restrict__ beU,
    const unsigned short* __restrict__ aggI_, const unsigned short* __restrict__ featI_,
    const int* __restrict__ cntI_, const float* __restrict__ WI,
    const float* __restrict__ beI,
    const float* __restrict__ loop_w, const float* __restrict__ h_bias,
    float* __restrict__ out)
{
    const int et = blockIdx.y;
    const unsigned short* __restrict__ agg  = et ? aggI_ : aggU_;
    const unsigned short* __restrict__ feat = et ? featI_ : featU_;
    const int* __restrict__ cntG            = et ? cntI_ : cntU_;
    const float* __restrict__ W             = et ? WI : WU;
    const float* __restrict__ b_et          = et ? beI : beU;
    float* __restrict__ outN = out + (et ? (size_t)N_USER * D : 0);

    __shared__ unsigned short sWt[64][72];   // W^T bf16:   sWt[n][k]
    __shared__ unsigned short sLt[64][72];   // loop^T bf16
    __shared__ float sbe[64], sbh[64];
    __shared__ int sCnt[64];

    const int tid = threadIdx.x;
    const int row0 = blockIdx.x * 64;

    for (int i = tid; i < 4096; i += 256) {
        int k = i >> 6, n = i & 63;
        sWt[n][k] = f32_to_bf16(W[i]);        // W[k][n]
        sLt[n][k] = f32_to_bf16(loop_w[i]);
    }
    if (tid < 64) {
        sbe[tid] = b_et[tid];
        sbh[tid] = h_bias[tid];
        int r = row0 + tid;
        sCnt[tid] = (r < N_NODE) ? cntG[r] : 0;
    }
    __syncthreads();

    const int wave = tid >> 6;
    const int lane = tid & 63;
    const int quad = lane >> 4;
    const int l16  = lane & 15;

    const int rowA = row0 + wave * 16 + l16;
    const int rA = (rowA < N_NODE) ? rowA : (N_NODE - 1);
    short8 aAgg0  = *(const short8*)(agg  + (size_t)rA * 64 +      quad * 8);
    short8 aAgg1  = *(const short8*)(agg  + (size_t)rA * 64 + 32 + quad * 8);
    short8 aFeat0 = *(const short8*)(feat + (size_t)rA * 64 +      quad * 8);
    short8 aFeat1 = *(const short8*)(feat + (size_t)rA * 64 + 32 + quad * 8);

    floatx4 acc[4];
    #pragma unroll
    for (int t = 0; t < 4; ++t) {
        const int n = t * 16 + l16;
        short8 bW0 = *(const short8*)&sWt[n][     quad * 8];
        short8 bW1 = *(const short8*)&sWt[n][32 + quad * 8];
        short8 bL0 = *(const short8*)&sLt[n][     quad * 8];
        short8 bL1 = *(const short8*)&sLt[n][32 + quad * 8];
        floatx4 a = {0.f, 0.f, 0.f, 0.f};
        a = __builtin_amdgcn_mfma_f32_16x16x32_bf16(aAgg0,  bW0, a, 0, 0, 0);
        a = __builtin_amdgcn_mfma_f32_16x16x32_bf16(aAgg1,  bW1, a, 0, 0, 0);
        a = __builtin_amdgcn_mfma_f32_16x16x32_bf16(aFeat0, bL0, a, 0, 0, 0);
        a = __builtin_amdgcn_mfma_f32_16x16x32_bf16(aFeat1, bL1, a, 0, 0, 0);
        acc[t] = a;
    }

    #pragma unroll
    for (int t = 0; t < 4; ++t) {
        const int col = t * 16 + l16;
        const float bh = sbh[col], be = sbe[col];
        #pragma unroll
        for (int i = 0; i < 4; ++i) {
            int lrow = wave * 16 + quad * 4 + i;
            int r = row0 + lrow;
            if (r < N_NODE) {
                float v = acc[t][i] + bh + (sCnt[lrow] > 0 ? be : 0.f);
                outN[(size_t)r * D + col] = v;
            }
        }
    }
}

// ---------------------------------------------------------------------------
extern "C" void kernel_launch(void* const* d_in, const int* in_sizes, int n_in,
                              void* d_out, int out_size, void* d_ws, size_t ws_size,
                              hipStream_t stream)
{
    const float* user_feat = (const float*)d_in[0];
    const float* item_feat = (const float*)d_in[1];
    const int*   rate_src  = (const int*)d_in[2];
    const int*   rate_dst  = (const int*)d_in[3];
    const int*   rev_src   = (const int*)d_in[4];
    const int*   rev_dst   = (const int*)d_in[5];
    const float* W_rate    = (const float*)d_in[6];
    const float* b_rate    = (const float*)d_in[7];
    const float* W_rev     = (const float*)d_in[8];
    const float* b_rev     = (const float*)d_in[9];
    const float* loop_w    = (const float*)d_in[10];
    const float* h_bias    = (const float*)d_in[11];
    float* out = (float*)d_out;

    // workspace layout (~51 MB)
    char* p = (char*)d_ws;
    ushort4* userB = (ushort4*)p; p += (size_t)N_USER * D * 2;                 // 6.4 MB
    ushort4* itemB = (ushort4*)p; p += (size_t)N_ITEM * D * 2;                 // 6.4 MB
    unsigned* gbinI = (unsigned*)p; p += (size_t)NBKT * BCAP * 4;              // 8.0 MB
    unsigned* gbinU = (unsigned*)p; p += (size_t)NBKT * BCAP * 4;              // 8.0 MB
    unsigned short* srtI = (unsigned short*)p; p += (size_t)NBKT * BCAP * 2;   // 4.0 MB
    unsigned short* srtU = (unsigned short*)p; p += (size_t)NBKT * BCAP * 2;   // 4.0 MB
    ushort4* aggI  = (ushort4*)p; p += (size_t)N_NODE * D * 2;                 // 6.4 MB
    ushort4* aggU  = (ushort4*)p; p += (size_t)N_NODE * D * 2;                 // 6.4 MB
    int* offI = (int*)p; p += (size_t)N_NODE * 4;
    int* offU = (int*)p; p += (size_t)N_NODE * 4;
    int* cntI = (int*)p; p += (size_t)N_NODE * 4;
    int* cntU = (int*)p; p += (size_t)N_NODE * 4;
    int* fcur = (int*)p; p += (size_t)(2 * NBKT) * 4;
    (void)ws_size;

    // fcur = per-bucket fill counts, zero-init (1.6 KB)
    hipMemsetAsync(fcur, 0, (size_t)(2 * NBKT) * sizeof(int), stream);

    // 1) merged chunk-sort (blocks [0, 2*NCH), dispatched first)
    //    + cast (blocks [2*NCH, ...), BW-bound, overlaps)
    cast_bin<<<dim3(2 * NCH + 2 * NCAST), 256, 0, stream>>>(
        (const float4*)user_feat, userB, (const float4*)item_feat, itemB,
        rate_src, rate_dst, gbinI,
        rev_src,  rev_dst,  gbinU, fcur);

    // 2) per-coarse-bucket counting sort -> u16 srt + off/cnt
    bucket_sort<<<dim3(NBKT, 2), 256, 0, stream>>>(
        gbinI, srtI, offI, cntI,
        gbinU, srtU, offU, cntU, fcur);

    // 3) raw-feature segment mean (bf16, unroll-4)
    aggregate_kernel<<<(N_USER + N_ITEM + 15) / 16, 256, 0, stream>>>(
        itemB, userB,
        offU, cntU, srtU,
        offI, cntI, srtI,
        aggU, aggI);

    // 4) final dual GEMM via MFMA (merged, fully writes d_out)
    final_gemm<<<dim3((N_NODE + 63) / 64, 2), 256, 0, stream>>>(
        (const unsigned short*)aggU, (const unsigned short*)userB, cntU, W_rev, b_rev,
        (const unsigned short*)aggI, (const unsigned short*)itemB, cntI, W_rate, b_rate,
        loop_w, h_bias, out);

    (void)in_sizes; (void)n_in; (void)out_size;
}

// Round 4
// 201.701 us; speedup vs baseline: 3.3068x; 1.0354x over previous
//
#include <hip/hip_runtime.h>

#define N_USER 50000
#define N_ITEM 50000
#define N_NODE 50000
#define N_EDGE 1600000
#define D 64

#define CB_SHIFT 8        // 256 nodes per coarse bucket
#define NBKT 196          // 196*256 = 50176 >= 50000
#define BCAP 10240        // per-bucket capacity (mean 8192, sigma~90 -> 22 sigma)
#define CHUNK 8192        // edges per chunk-sort block
#define NCH ((N_EDGE + CHUNK - 1) / CHUNK)     // 196
#define NCAST 3125        // cast blocks per table: 50000*16/256 exactly

typedef __attribute__((ext_vector_type(8))) short short8;    // 8 bf16 = 4 VGPR
typedef __attribute__((ext_vector_type(4))) float floatx4;   // mfma acc

__device__ __forceinline__ unsigned short f32_to_bf16(float x) {
    unsigned u = __float_as_uint(x);
    unsigned r = (u + 0x7FFFu + ((u >> 16) & 1u)) >> 16;   // RNE
    return (unsigned short)r;
}
__device__ __forceinline__ float bf16_to_f32(unsigned short h) {
    return __uint_as_float(((unsigned)h) << 16);
}

// accumulate one uint (2 packed bf16) into a[k], a[k+1] -- 2 bitops + 2 adds
__device__ __forceinline__ void acc2(float* a, int k, unsigned u) {
    a[k]     += __uint_as_float(u << 16);
    a[k + 1] += __uint_as_float(u & 0xFFFF0000u);
}
__device__ __forceinline__ void acc8(float* a, uint4 w) {
    acc2(a, 0, w.x); acc2(a, 2, w.y); acc2(a, 4, w.z); acc2(a, 6, w.w);
}

// ---------------------------------------------------------------------------
// Kernel 1 (merged): blocks [0, 2*NCH) chunk-sort 8192 edges each into coarse
// dst-buckets ENTIRELY IN LDS, then copy per-bucket segments (~42 entries,
// 168 B) to reserved contiguous windows in gbin. Every global write is a
// coalesced segment copy -- no per-edge scattered stores (round-2 lesson:
// scattered small stores cost a full 64B line writeback each).
// Blocks [2*NCH, ...) cast fp32->bf16 feature tables (BW-bound, overlaps).
// ---------------------------------------------------------------------------
__global__ __launch_bounds__(256) void cast_bin(
    const float4* __restrict__ fU, ushort4* __restrict__ bU,
    const float4* __restrict__ fI, ushort4* __restrict__ bI,
    const int* __restrict__ srcA, const int* __restrict__ dstA, unsigned* __restrict__ gbinA,
    const int* __restrict__ srcB, const int* __restrict__ dstB, unsigned* __restrict__ gbinB,
    int* __restrict__ fcur)
{
    __shared__ unsigned lbin[CHUNK];   // 32 KB staging
    __shared__ int hist[NBKT];
    __shared__ int lofs[NBKT];
    __shared__ int lcur[NBKT];
    __shared__ int gbase[NBKT];
    __shared__ int sc[256];

    const int id = blockIdx.x;

    if (id >= 2 * NCH) {
        // cast role: pure streaming, exact bounds (NCAST*256 == N_NODE*16)
        const int cid = id - 2 * NCH;
        const int et = (cid >= NCAST) ? 1 : 0;
        const float4* __restrict__ in = et ? fI : fU;
        ushort4* __restrict__ out     = et ? bI : bU;
        int i = (cid - et * NCAST) * 256 + threadIdx.x;
        float4 v = in[i];
        ushort4 o;
        o.x = f32_to_bf16(v.x); o.y = f32_to_bf16(v.y);
        o.z = f32_to_bf16(v.z); o.w = f32_to_bf16(v.w);
        out[i] = o;
        return;
    }

    // chunk-sort role
    const int et = (id >= NCH) ? 1 : 0;
    const int chunk = id - et * NCH;
    const int* __restrict__ src = et ? srcB : srcA;
    const int* __restrict__ dst = et ? dstB : dstA;
    unsigned* __restrict__ gbin = et ? gbinB : gbinA;
    int* __restrict__ fc = fcur + et * NBKT;

    const int base = chunk * CHUNK;
    const int nE = min(CHUNK, N_EDGE - base);
    const int n4 = nE >> 2;                      // nE % 4 == 0 always here
    const int4* dst4 = (const int4*)(dst + base);
    const int4* src4 = (const int4*)(src + base);
    const int tid = threadIdx.x;

    for (int i = tid; i < NBKT; i += 256) hist[i] = 0;
    __syncthreads();

    // pass 1: count per coarse bucket
    for (int i = tid; i < n4; i += 256) {
        int4 d = dst4[i];
        atomicAdd(&hist[d.x >> CB_SHIFT], 1);
        atomicAdd(&hist[d.y >> CB_SHIFT], 1);
        atomicAdd(&hist[d.z >> CB_SHIFT], 1);
        atomicAdd(&hist[d.w >> CB_SHIFT], 1);
    }
    __syncthreads();

    // exclusive scan over 196 counts (256-wide Hillis-Steele)
    int v = (tid < NBKT) ? hist[tid] : 0;
    sc[tid] = v;
    __syncthreads();
    for (int o = 1; o < 256; o <<= 1) {
        int t = (tid >= o) ? sc[tid - o] : 0;
        __syncthreads();
        sc[tid] += t;
        __syncthreads();
    }
    if (tid < NBKT) {
        int excl = sc[tid] - v;
        lofs[tid] = excl;
        lcur[tid] = excl;
        // reserve contiguous global window for this chunk's segment
        gbase[tid] = v ? (tid * BCAP + atomicAdd(&fc[tid], v)) : 0;
    }
    __syncthreads();

    // pass 2: scatter packed (dst<<16)|src into LDS (re-read edges, L2-hot)
    for (int i = tid; i < n4; i += 256) {
        int4 d = dst4[i];
        int4 s = src4[i];
        { int p = atomicAdd(&lcur[d.x >> CB_SHIFT], 1); lbin[p] = ((unsigned)d.x << 16) | (unsigned)s.x; }
        { int p = atomicAdd(&lcur[d.y >> CB_SHIFT], 1); lbin[p] = ((unsigned)d.y << 16) | (unsigned)s.y; }
        { int p = atomicAdd(&lcur[d.z >> CB_SHIFT], 1); lbin[p] = ((unsigned)d.z << 16) | (unsigned)s.z; }
        { int p = atomicAdd(&lcur[d.w >> CB_SHIFT], 1); lbin[p] = ((unsigned)d.w << 16) | (unsigned)s.w; }
    }
    __syncthreads();

    // copy out: one wave per bucket segment, contiguous global writes
    const int wv = tid >> 6, ln = tid & 63;
    for (int b = wv; b < NBKT; b += 4) {
        const int s0 = lofs[b], c = hist[b], g = gbase[b];
        for (int t = ln; t < c; t += 64) gbin[g + t] = lbin[s0 + t];
    }
}

// ---------------------------------------------------------------------------
// Kernel 2: per-coarse-bucket counting sort -> u16 srt (LDS-staged, coalesced
// write-out) + per-node off/cnt. One block per (bucket, etype), ~8192 edges,
// window-contiguous global reads.
// ---------------------------------------------------------------------------
__global__ __launch_bounds__(256) void bucket_sort(
    const unsigned* __restrict__ gbinI, unsigned short* __restrict__ srtI,
    int* __restrict__ offI, int* __restrict__ cntI,
    const unsigned* __restrict__ gbinU, unsigned short* __restrict__ srtU,
    int* __restrict__ offU, int* __restrict__ cntU,
    const int* __restrict__ fcur)
{
    const int et = blockIdx.y;
    const unsigned* __restrict__ gbin = et ? gbinU : gbinI;
    unsigned short* __restrict__ srt  = et ? srtU : srtI;
    int* __restrict__ off   = et ? offU : offI;
    int* __restrict__ cntG  = et ? cntU : cntI;
    const int b = blockIdx.x;
    const int startg = b * BCAP;
    const int n = fcur[et * NBKT + b];
    const int nodebase = b << CB_SHIFT;
    const int tid = threadIdx.x;

    __shared__ int cnt[256];
    __shared__ int sc[256];
    __shared__ int pos[256];
    __shared__ unsigned short lsrt[BCAP];   // 20 KB staging

    cnt[tid] = 0;
    __syncthreads();

    for (int i = tid; i < n; i += 256)
        atomicAdd(&cnt[(int)(gbin[startg + i] >> 16) - nodebase], 1);
    __syncthreads();

    int v = cnt[tid];
    sc[tid] = v;
    __syncthreads();
    for (int o = 1; o < 256; o <<= 1) {
        int t = (tid >= o) ? sc[tid - o] : 0;
        __syncthreads();
        sc[tid] += t;
        __syncthreads();
    }
    {
        int excl = sc[tid] - v;
        pos[tid] = excl;
        int node = nodebase + tid;
        if (node < N_NODE) { off[node] = startg + excl; cntG[node] = v; }
    }
    __syncthreads();

    for (int i = tid; i < n; i += 256) {
        unsigned p = gbin[startg + i];                  // L2-hot re-read
        int q = atomicAdd(&pos[(int)(p >> 16) - nodebase], 1);
        lsrt[q] = (unsigned short)(p & 0xFFFFu);        // LDS scatter
    }
    __syncthreads();

    for (int i = tid; i < n; i += 256) srt[startg + i] = lsrt[i];   // coalesced
}

// ---------------------------------------------------------------------------
// Kernel 3: raw-feature segment mean (bf16 gather). 8 lanes/node, uint4
// (16 B) per lane per edge, unroll-4 -> 64 B in flight per thread (2x the
// old 16-lane/ushort4 geometry at the same resident-wave count). Two
// accumulator sets break add dependency chains.
// ---------------------------------------------------------------------------
__global__ __launch_bounds__(256) void aggregate_kernel(
    const uint4* __restrict__ itemB,   // sources for user dst (rev)
    const uint4* __restrict__ userB,   // sources for item dst (rate)
    const int* __restrict__ offU, const int* __restrict__ cntU, const unsigned short* __restrict__ srtU,
    const int* __restrict__ offI, const int* __restrict__ cntI, const unsigned short* __restrict__ srtI,
    uint4* __restrict__ aggU, uint4* __restrict__ aggI)
{
    int g = blockIdx.x * 32 + (threadIdx.x >> 3);   // 32 nodes/block
    if (g >= N_USER + N_ITEM) return;
    const int lane = threadIdx.x & 7;               // 8 lanes/node, 16 B each

    const bool isUser = (g < N_USER);
    const int d = isUser ? g : g - N_USER;
    const uint4* __restrict__ tab = isUser ? itemB : userB;
    const int* __restrict__ off     = isUser ? offU : offI;
    const int* __restrict__ cntG    = isUser ? cntU : cntI;
    const unsigned short* __restrict__ srt = isUser ? srtU : srtI;
    uint4* __restrict__ agg         = isUser ? aggU : aggI;

    const int start = off[d];
    const int c     = cntG[d];
    const int end   = start + c;

    float aA[8] = {0.f, 0.f, 0.f, 0.f, 0.f, 0.f, 0.f, 0.f};
    float aB[8] = {0.f, 0.f, 0.f, 0.f, 0.f, 0.f, 0.f, 0.f};

    int e = start;
    for (; e + 4 <= end; e += 4) {
        int s0 = (int)srt[e],     s1 = (int)srt[e + 1];
        int s2 = (int)srt[e + 2], s3 = (int)srt[e + 3];
        uint4 w0 = tab[(size_t)s0 * 8 + lane];
        uint4 w1 = tab[(size_t)s1 * 8 + lane];
        uint4 w2 = tab[(size_t)s2 * 8 + lane];
        uint4 w3 = tab[(size_t)s3 * 8 + lane];
        acc8(aA, w0); acc8(aB, w1); acc8(aA, w2); acc8(aB, w3);
    }
    for (; e < end; ++e) {
        uint4 w = tab[(size_t)(int)srt[e] * 8 + lane];
        acc8(aA, w);
    }
    #pragma unroll
    for (int k = 0; k < 8; ++k) aA[k] += aB[k];

    const float inv = (c > 0) ? 1.0f / (float)c : 0.0f;
    uint4 o;
    o.x = (unsigned)f32_to_bf16(aA[0] * inv) | ((unsigned)f32_to_bf16(aA[1] * inv) << 16);
    o.y = (unsigned)f32_to_bf16(aA[2] * inv) | ((unsigned)f32_to_bf16(aA[3] * inv) << 16);
    o.z = (unsigned)f32_to_bf16(aA[4] * inv) | ((unsigned)f32_to_bf16(aA[5] * inv) << 16);
    o.w = (unsigned)f32_to_bf16(aA[6] * inv) | ((unsigned)f32_to_bf16(aA[7] * inv) << 16);
    agg[(size_t)d * 8 + lane] = o;
}

// ---------------------------------------------------------------------------
// Kernel 4: final dual GEMM via MFMA (16x16x32 bf16). 64 rows/block, 4 waves.
// D = agg@W + feat@loop (+ biases in epilogue). Layouts guide-verified.
// ---------------------------------------------------------------------------
__global__ __launch_bounds__(256, 4) void final_gemm(
    const unsigned short* __restrict__ aggU_, const unsigned short* __restrict__ featU_,
    const int* __restrict__ cntU_, const float* __restrict__ WU,
    const float* __restrict__ beU,
    const unsigned short* __restrict__ aggI_, const unsigned short* __restrict__ featI_,
    const int* __restrict__ cntI_, const float* __restrict__ WI,
    const float* __restrict__ beI,
    const float* __restrict__ loop_w, const float* __restrict__ h_bias,
    float* __restrict__ out)
{
    const int et = blockIdx.y;
    const unsigned short* __restrict__ agg  = et ? aggI_ : aggU_;
    const unsigned short* __restrict__ feat = et ? featI_ : featU_;
    const int* __restrict__ cntG            = et ? cntI_ : cntU_;
    const float* __restrict__ W             = et ? WI : WU;
    const float* __restrict__ b_et          = et ? beI : beU;
    float* __restrict__ outN = out + (et ? (size_t)N_USER * D : 0);

    __shared__ unsigned short sWt[64][72];   // W^T bf16:   sWt[n][k]
    __shared__ unsigned short sLt[64][72];   // loop^T bf16
    __shared__ float sbe[64], sbh[64];
    __shared__ int sCnt[64];

    const int tid = threadIdx.x;
    const int row0 = blockIdx.x * 64;

    for (int i = tid; i < 4096; i += 256) {
        int k = i >> 6, n = i & 63;
        sWt[n][k] = f32_to_bf16(W[i]);        // W[k][n]
        sLt[n][k] = f32_to_bf16(loop_w[i]);
    }
    if (tid < 64) {
        sbe[tid] = b_et[tid];
        sbh[tid] = h_bias[tid];
        int r = row0 + tid;
        sCnt[tid] = (r < N_NODE) ? cntG[r] : 0;
    }
    __syncthreads();

    const int wave = tid >> 6;
    const int lane = tid & 63;
    const int quad = lane >> 4;
    const int l16  = lane & 15;

    const int rowA = row0 + wave * 16 + l16;
    const int rA = (rowA < N_NODE) ? rowA : (N_NODE - 1);
    short8 aAgg0  = *(const short8*)(agg  + (size_t)rA * 64 +      quad * 8);
    short8 aAgg1  = *(const short8*)(agg  + (size_t)rA * 64 + 32 + quad * 8);
    short8 aFeat0 = *(const short8*)(feat + (size_t)rA * 64 +      quad * 8);
    short8 aFeat1 = *(const short8*)(feat + (size_t)rA * 64 + 32 + quad * 8);

    floatx4 acc[4];
    #pragma unroll
    for (int t = 0; t < 4; ++t) {
        const int n = t * 16 + l16;
        short8 bW0 = *(const short8*)&sWt[n][     quad * 8];
        short8 bW1 = *(const short8*)&sWt[n][32 + quad * 8];
        short8 bL0 = *(const short8*)&sLt[n][     quad * 8];
        short8 bL1 = *(const short8*)&sLt[n][32 + quad * 8];
        floatx4 a = {0.f, 0.f, 0.f, 0.f};
        a = __builtin_amdgcn_mfma_f32_16x16x32_bf16(aAgg0,  bW0, a, 0, 0, 0);
        a = __builtin_amdgcn_mfma_f32_16x16x32_bf16(aAgg1,  bW1, a, 0, 0, 0);
        a = __builtin_amdgcn_mfma_f32_16x16x32_bf16(aFeat0, bL0, a, 0, 0, 0);
        a = __builtin_amdgcn_mfma_f32_16x16x32_bf16(aFeat1, bL1, a, 0, 0, 0);
        acc[t] = a;
    }

    #pragma unroll
    for (int t = 0; t < 4; ++t) {
        const int col = t * 16 + l16;
        const float bh = sbh[col], be = sbe[col];
        #pragma unroll
        for (int i = 0; i < 4; ++i) {
            int lrow = wave * 16 + quad * 4 + i;
            int r = row0 + lrow;
            if (r < N_NODE) {
                float v = acc[t][i] + bh + (sCnt[lrow] > 0 ? be : 0.f);
                outN[(size_t)r * D + col] = v;
            }
        }
    }
}

// ---------------------------------------------------------------------------
extern "C" void kernel_launch(void* const* d_in, const int* in_sizes, int n_in,
                              void* d_out, int out_size, void* d_ws, size_t ws_size,
                              hipStream_t stream)
{
    const float* user_feat = (const float*)d_in[0];
    const float* item_feat = (const float*)d_in[1];
    const int*   rate_src  = (const int*)d_in[2];
    const int*   rate_dst  = (const int*)d_in[3];
    const int*   rev_src   = (const int*)d_in[4];
    const int*   rev_dst   = (const int*)d_in[5];
    const float* W_rate    = (const float*)d_in[6];
    const float* b_rate    = (const float*)d_in[7];
    const float* W_rev     = (const float*)d_in[8];
    const float* b_rev     = (const float*)d_in[9];
    const float* loop_w    = (const float*)d_in[10];
    const float* h_bias    = (const float*)d_in[11];
    float* out = (float*)d_out;

    // workspace layout (~51 MB)
    char* p = (char*)d_ws;
    ushort4* userB = (ushort4*)p; p += (size_t)N_USER * D * 2;                 // 6.4 MB
    ushort4* itemB = (ushort4*)p; p += (size_t)N_ITEM * D * 2;                 // 6.4 MB
    unsigned* gbinI = (unsigned*)p; p += (size_t)NBKT * BCAP * 4;              // 8.0 MB
    unsigned* gbinU = (unsigned*)p; p += (size_t)NBKT * BCAP * 4;              // 8.0 MB
    unsigned short* srtI = (unsigned short*)p; p += (size_t)NBKT * BCAP * 2;   // 4.0 MB
    unsigned short* srtU = (unsigned short*)p; p += (size_t)NBKT * BCAP * 2;   // 4.0 MB
    ushort4* aggI  = (ushort4*)p; p += (size_t)N_NODE * D * 2;                 // 6.4 MB
    ushort4* aggU  = (ushort4*)p; p += (size_t)N_NODE * D * 2;                 // 6.4 MB
    int* offI = (int*)p; p += (size_t)N_NODE * 4;
    int* offU = (int*)p; p += (size_t)N_NODE * 4;
    int* cntI = (int*)p; p += (size_t)N_NODE * 4;
    int* cntU = (int*)p; p += (size_t)N_NODE * 4;
    int* fcur = (int*)p; p += (size_t)(2 * NBKT) * 4;
    (void)ws_size;

    // fcur = per-bucket fill counts, zero-init (1.6 KB)
    hipMemsetAsync(fcur, 0, (size_t)(2 * NBKT) * sizeof(int), stream);

    // 1) merged chunk-sort (blocks [0, 2*NCH), dispatched first)
    //    + cast (blocks [2*NCH, ...), BW-bound, overlaps)
    cast_bin<<<dim3(2 * NCH + 2 * NCAST), 256, 0, stream>>>(
        (const float4*)user_feat, userB, (const float4*)item_feat, itemB,
        rate_src, rate_dst, gbinI,
        rev_src,  rev_dst,  gbinU, fcur);

    // 2) per-coarse-bucket counting sort -> u16 srt + off/cnt
    bucket_sort<<<dim3(NBKT, 2), 256, 0, stream>>>(
        gbinI, srtI, offI, cntI,
        gbinU, srtU, offU, cntU, fcur);

    // 3) raw-feature segment mean (bf16, 8 lanes/node, 16 B loads, unroll-4)
    aggregate_kernel<<<(N_USER + N_ITEM + 31) / 32, 256, 0, stream>>>(
        (const uint4*)itemB, (const uint4*)userB,
        offU, cntU, srtU,
        offI, cntI, srtI,
        (uint4*)aggU, (uint4*)aggI);

    // 4) final dual GEMM via MFMA (merged, fully writes d_out)
    final_gemm<<<dim3((N_NODE + 63) / 64, 2), 256, 0, stream>>>(
        (const unsigned short*)aggU, (const unsigned short*)userB, cntU, W_rev, b_rev,
        (const unsigned short*)aggI, (const unsigned short*)itemB, cntI, W_rate, b_rate,
        loop_w, h_bias, out);

    (void)in_sizes; (void)n_in; (void)out_size;
}

// Round 5
// 197.613 us; speedup vs baseline: 3.3752x; 1.0207x over previous
//
#include <hip/hip_runtime.h>

#define N_USER 50000
#define N_ITEM 50000
#define N_NODE 50000
#define N_EDGE 1600000
#define D 64

#define CB_SHIFT 8        // 256 nodes per coarse bucket
#define NBKT 196          // 196*256 = 50176 >= 50000
#define BCAP 10240        // per-bucket capacity (mean 8192, sigma~90 -> 22 sigma)
#define CHUNK 8192        // edges per chunk-sort block
#define NCH ((N_EDGE + CHUNK - 1) / CHUNK)     // 196
#define NCAST 3125        // cast blocks per table: 50000*16/256 exactly

typedef __attribute__((ext_vector_type(8))) short short8;    // 8 bf16 = 4 VGPR
typedef __attribute__((ext_vector_type(4))) float floatx4;   // mfma acc

__device__ __forceinline__ unsigned short f32_to_bf16(float x) {
    unsigned u = __float_as_uint(x);
    unsigned r = (u + 0x7FFFu + ((u >> 16) & 1u)) >> 16;   // RNE
    return (unsigned short)r;
}
__device__ __forceinline__ float bf16_to_f32(unsigned short h) {
    return __uint_as_float(((unsigned)h) << 16);
}

// accumulate one uint (2 packed bf16) into a[k], a[k+1] -- 2 bitops + 2 adds
__device__ __forceinline__ void acc2(float* a, int k, unsigned u) {
    a[k]     += __uint_as_float(u << 16);
    a[k + 1] += __uint_as_float(u & 0xFFFF0000u);
}
__device__ __forceinline__ void acc8(float* a, uint4 w) {
    acc2(a, 0, w.x); acc2(a, 2, w.y); acc2(a, 4, w.z); acc2(a, 6, w.w);
}

// ---------------------------------------------------------------------------
// Kernel 1 (merged): blocks [0, 2*NCH) chunk-sort 8192 edges each into coarse
// dst-buckets ENTIRELY IN LDS, then copy per-bucket segments (~42 entries,
// 168 B) to reserved contiguous windows in gbin. Every global write is a
// coalesced segment copy -- no per-edge scattered stores (round-2 lesson:
// scattered small stores cost a full 64B line writeback each).
// Blocks [2*NCH, ...) cast fp32->bf16 feature tables (BW-bound, overlaps).
// ---------------------------------------------------------------------------
__global__ __launch_bounds__(256) void cast_bin(
    const float4* __restrict__ fU, ushort4* __restrict__ bU,
    const float4* __restrict__ fI, ushort4* __restrict__ bI,
    const int* __restrict__ srcA, const int* __restrict__ dstA, unsigned* __restrict__ gbinA,
    const int* __restrict__ srcB, const int* __restrict__ dstB, unsigned* __restrict__ gbinB,
    int* __restrict__ fcur)
{
    __shared__ unsigned lbin[CHUNK];   // 32 KB staging
    __shared__ int hist[NBKT];
    __shared__ int lofs[NBKT];
    __shared__ int lcur[NBKT];
    __shared__ int gbase[NBKT];
    __shared__ int sc[256];

    const int id = blockIdx.x;

    if (id >= 2 * NCH) {
        // cast role: pure streaming, exact bounds (NCAST*256 == N_NODE*16)
        const int cid = id - 2 * NCH;
        const int et = (cid >= NCAST) ? 1 : 0;
        const float4* __restrict__ in = et ? fI : fU;
        ushort4* __restrict__ out     = et ? bI : bU;
        int i = (cid - et * NCAST) * 256 + threadIdx.x;
        float4 v = in[i];
        ushort4 o;
        o.x = f32_to_bf16(v.x); o.y = f32_to_bf16(v.y);
        o.z = f32_to_bf16(v.z); o.w = f32_to_bf16(v.w);
        out[i] = o;
        return;
    }

    // chunk-sort role
    const int et = (id >= NCH) ? 1 : 0;
    const int chunk = id - et * NCH;
    const int* __restrict__ src = et ? srcB : srcA;
    const int* __restrict__ dst = et ? dstB : dstA;
    unsigned* __restrict__ gbin = et ? gbinB : gbinA;
    int* __restrict__ fc = fcur + et * NBKT;

    const int base = chunk * CHUNK;
    const int nE = min(CHUNK, N_EDGE - base);
    const int n4 = nE >> 2;                      // nE % 4 == 0 always here
    const int4* dst4 = (const int4*)(dst + base);
    const int4* src4 = (const int4*)(src + base);
    const int tid = threadIdx.x;

    for (int i = tid; i < NBKT; i += 256) hist[i] = 0;
    __syncthreads();

    // pass 1: count per coarse bucket
    for (int i = tid; i < n4; i += 256) {
        int4 d = dst4[i];
        atomicAdd(&hist[d.x >> CB_SHIFT], 1);
        atomicAdd(&hist[d.y >> CB_SHIFT], 1);
        atomicAdd(&hist[d.z >> CB_SHIFT], 1);
        atomicAdd(&hist[d.w >> CB_SHIFT], 1);
    }
    __syncthreads();

    // exclusive scan over 196 counts (256-wide Hillis-Steele)
    int v = (tid < NBKT) ? hist[tid] : 0;
    sc[tid] = v;
    __syncthreads();
    for (int o = 1; o < 256; o <<= 1) {
        int t = (tid >= o) ? sc[tid - o] : 0;
        __syncthreads();
        sc[tid] += t;
        __syncthreads();
    }
    if (tid < NBKT) {
        int excl = sc[tid] - v;
        lofs[tid] = excl;
        lcur[tid] = excl;
        // reserve contiguous global window for this chunk's segment
        gbase[tid] = v ? (tid * BCAP + atomicAdd(&fc[tid], v)) : 0;
    }
    __syncthreads();

    // pass 2: scatter packed (dst<<16)|src into LDS (re-read edges, L2-hot)
    for (int i = tid; i < n4; i += 256) {
        int4 d = dst4[i];
        int4 s = src4[i];
        { int p = atomicAdd(&lcur[d.x >> CB_SHIFT], 1); lbin[p] = ((unsigned)d.x << 16) | (unsigned)s.x; }
        { int p = atomicAdd(&lcur[d.y >> CB_SHIFT], 1); lbin[p] = ((unsigned)d.y << 16) | (unsigned)s.y; }
        { int p = atomicAdd(&lcur[d.z >> CB_SHIFT], 1); lbin[p] = ((unsigned)d.z << 16) | (unsigned)s.z; }
        { int p = atomicAdd(&lcur[d.w >> CB_SHIFT], 1); lbin[p] = ((unsigned)d.w << 16) | (unsigned)s.w; }
    }
    __syncthreads();

    // copy out: one wave per bucket segment, contiguous global writes
    const int wv = tid >> 6, ln = tid & 63;
    for (int b = wv; b < NBKT; b += 4) {
        const int s0 = lofs[b], c = hist[b], g = gbase[b];
        for (int t = ln; t < c; t += 64) gbin[g + t] = lbin[s0 + t];
    }
}

// ---------------------------------------------------------------------------
// Kernel 2: per-coarse-bucket counting sort -> u16 srt (LDS-staged, coalesced
// write-out) + per-node off/cnt. One block per (bucket, etype), ~8192 edges,
// window-contiguous global reads.
// ---------------------------------------------------------------------------
__global__ __launch_bounds__(256) void bucket_sort(
    const unsigned* __restrict__ gbinI, unsigned short* __restrict__ srtI,
    int* __restrict__ offI, int* __restrict__ cntI,
    const unsigned* __restrict__ gbinU, unsigned short* __restrict__ srtU,
    int* __restrict__ offU, int* __restrict__ cntU,
    const int* __restrict__ fcur)
{
    const int et = blockIdx.y;
    const unsigned* __restrict__ gbin = et ? gbinU : gbinI;
    unsigned short* __restrict__ srt  = et ? srtU : srtI;
    int* __restrict__ off   = et ? offU : offI;
    int* __restrict__ cntG  = et ? cntU : cntI;
    const int b = blockIdx.x;
    const int startg = b * BCAP;
    const int n = fcur[et * NBKT + b];
    const int nodebase = b << CB_SHIFT;
    const int tid = threadIdx.x;

    __shared__ int cnt[256];
    __shared__ int sc[256];
    __shared__ int pos[256];
    __shared__ unsigned short lsrt[BCAP];   // 20 KB staging

    cnt[tid] = 0;
    __syncthreads();

    for (int i = tid; i < n; i += 256)
        atomicAdd(&cnt[(int)(gbin[startg + i] >> 16) - nodebase], 1);
    __syncthreads();

    int v = cnt[tid];
    sc[tid] = v;
    __syncthreads();
    for (int o = 1; o < 256; o <<= 1) {
        int t = (tid >= o) ? sc[tid - o] : 0;
        __syncthreads();
        sc[tid] += t;
        __syncthreads();
    }
    {
        int excl = sc[tid] - v;
        pos[tid] = excl;
        int node = nodebase + tid;
        if (node < N_NODE) { off[node] = startg + excl; cntG[node] = v; }
    }
    __syncthreads();

    for (int i = tid; i < n; i += 256) {
        unsigned p = gbin[startg + i];                  // L2-hot re-read
        int q = atomicAdd(&pos[(int)(p >> 16) - nodebase], 1);
        lsrt[q] = (unsigned short)(p & 0xFFFFu);        // LDS scatter
    }
    __syncthreads();

    for (int i = tid; i < n; i += 256) srt[startg + i] = lsrt[i];   // coalesced
}

// ---------------------------------------------------------------------------
// Kernel 3: raw-feature segment mean (bf16 gather). 8 lanes/node, uint4
// (16 B) per lane per edge. UNROLL-8 TWO-PHASE: issue all eight row loads
// (128 B in flight per thread), then accumulate -- discriminates
// latency-bound (should drop to ~33 us) vs L3-throughput-bound (null).
// ---------------------------------------------------------------------------
__global__ __launch_bounds__(256) void aggregate_kernel(
    const uint4* __restrict__ itemB,   // sources for user dst (rev)
    const uint4* __restrict__ userB,   // sources for item dst (rate)
    const int* __restrict__ offU, const int* __restrict__ cntU, const unsigned short* __restrict__ srtU,
    const int* __restrict__ offI, const int* __restrict__ cntI, const unsigned short* __restrict__ srtI,
    uint4* __restrict__ aggU, uint4* __restrict__ aggI)
{
    int g = blockIdx.x * 32 + (threadIdx.x >> 3);   // 32 nodes/block
    if (g >= N_USER + N_ITEM) return;
    const int lane = threadIdx.x & 7;               // 8 lanes/node, 16 B each

    const bool isUser = (g < N_USER);
    const int d = isUser ? g : g - N_USER;
    const uint4* __restrict__ tab = isUser ? itemB : userB;
    const int* __restrict__ off     = isUser ? offU : offI;
    const int* __restrict__ cntG    = isUser ? cntU : cntI;
    const unsigned short* __restrict__ srt = isUser ? srtU : srtI;
    uint4* __restrict__ agg         = isUser ? aggU : aggI;

    const int start = off[d];
    const int c     = cntG[d];
    const int end   = start + c;

    float aA[8] = {0.f, 0.f, 0.f, 0.f, 0.f, 0.f, 0.f, 0.f};
    float aB[8] = {0.f, 0.f, 0.f, 0.f, 0.f, 0.f, 0.f, 0.f};

    int e = start;
    // main: 8 edges/iteration, two-phase (8 independent 16B loads in flight)
    for (; e + 8 <= end; e += 8) {
        int s0 = (int)srt[e],     s1 = (int)srt[e + 1];
        int s2 = (int)srt[e + 2], s3 = (int)srt[e + 3];
        int s4 = (int)srt[e + 4], s5 = (int)srt[e + 5];
        int s6 = (int)srt[e + 6], s7 = (int)srt[e + 7];
        uint4 w0 = tab[(size_t)s0 * 8 + lane];
        uint4 w1 = tab[(size_t)s1 * 8 + lane];
        uint4 w2 = tab[(size_t)s2 * 8 + lane];
        uint4 w3 = tab[(size_t)s3 * 8 + lane];
        uint4 w4 = tab[(size_t)s4 * 8 + lane];
        uint4 w5 = tab[(size_t)s5 * 8 + lane];
        uint4 w6 = tab[(size_t)s6 * 8 + lane];
        uint4 w7 = tab[(size_t)s7 * 8 + lane];
        acc8(aA, w0); acc8(aB, w1); acc8(aA, w2); acc8(aB, w3);
        acc8(aA, w4); acc8(aB, w5); acc8(aA, w6); acc8(aB, w7);
    }
    // 4-edge tail group
    for (; e + 4 <= end; e += 4) {
        int s0 = (int)srt[e],     s1 = (int)srt[e + 1];
        int s2 = (int)srt[e + 2], s3 = (int)srt[e + 3];
        uint4 w0 = tab[(size_t)s0 * 8 + lane];
        uint4 w1 = tab[(size_t)s1 * 8 + lane];
        uint4 w2 = tab[(size_t)s2 * 8 + lane];
        uint4 w3 = tab[(size_t)s3 * 8 + lane];
        acc8(aA, w0); acc8(aB, w1); acc8(aA, w2); acc8(aB, w3);
    }
    // scalar tail
    for (; e < end; ++e) {
        uint4 w = tab[(size_t)(int)srt[e] * 8 + lane];
        acc8(aA, w);
    }
    #pragma unroll
    for (int k = 0; k < 8; ++k) aA[k] += aB[k];

    const float inv = (c > 0) ? 1.0f / (float)c : 0.0f;
    uint4 o;
    o.x = (unsigned)f32_to_bf16(aA[0] * inv) | ((unsigned)f32_to_bf16(aA[1] * inv) << 16);
    o.y = (unsigned)f32_to_bf16(aA[2] * inv) | ((unsigned)f32_to_bf16(aA[3] * inv) << 16);
    o.z = (unsigned)f32_to_bf16(aA[4] * inv) | ((unsigned)f32_to_bf16(aA[5] * inv) << 16);
    o.w = (unsigned)f32_to_bf16(aA[6] * inv) | ((unsigned)f32_to_bf16(aA[7] * inv) << 16);
    agg[(size_t)d * 8 + lane] = o;
}

// ---------------------------------------------------------------------------
// Kernel 4: final dual GEMM via MFMA (16x16x32 bf16). 64 rows/block, 4 waves.
// D = agg@W + feat@loop (+ biases in epilogue). Layouts guide-verified.
// ---------------------------------------------------------------------------
__global__ __launch_bounds__(256, 4) void final_gemm(
    const unsigned short* __restrict__ aggU_, const unsigned short* __restrict__ featU_,
    const int* __restrict__ cntU_, const float* __restrict__ WU,
    const float* __restrict__ beU,
    const unsigned short* __restrict__ aggI_, const unsigned short* __restrict__ featI_,
    const int* __restrict__ cntI_, const float* __restrict__ WI,
    const float* __restrict__ beI,
    const float* __restrict__ loop_w, const float* __restrict__ h_bias,
    float* __restrict__ out)
{
    const int et = blockIdx.y;
    const unsigned short* __restrict__ agg  = et ? aggI_ : aggU_;
    const unsigned short* __restrict__ feat = et ? featI_ : featU_;
    const int* __restrict__ cntG            = et ? cntI_ : cntU_;
    const float* __restrict__ W             = et ? WI : WU;
    const float* __restrict__ b_et          = et ? beI : beU;
    float* __restrict__ outN = out + (et ? (size_t)N_USER * D : 0);

    __shared__ unsigned short sWt[64][72];   // W^T bf16:   sWt[n][k]
    __shared__ unsigned short sLt[64][72];   // loop^T bf16
    __shared__ float sbe[64], sbh[64];
    __shared__ int sCnt[64];

    const int tid = threadIdx.x;
    const int row0 = blockIdx.x * 64;

    for (int i = tid; i < 4096; i += 256) {
        int k = i >> 6, n = i & 63;
        sWt[n][k] = f32_to_bf16(W[i]);        // W[k][n]
        sLt[n][k] = f32_to_bf16(loop_w[i]);
    }
    if (tid < 64) {
        sbe[tid] = b_et[tid];
        sbh[tid] = h_bias[tid];
        int r = row0 + tid;
        sCnt[tid] = (r < N_NODE) ? cntG[r] : 0;
    }
    __syncthreads();

    const int wave = tid >> 6;
    const int lane = tid & 63;
    const int quad = lane >> 4;
    const int l16  = lane & 15;

    const int rowA = row0 + wave * 16 + l16;
    const int rA = (rowA < N_NODE) ? rowA : (N_NODE - 1);
    short8 aAgg0  = *(const short8*)(agg  + (size_t)rA * 64 +      quad * 8);
    short8 aAgg1  = *(const short8*)(agg  + (size_t)rA * 64 + 32 + quad * 8);
    short8 aFeat0 = *(const short8*)(feat + (size_t)rA * 64 +      quad * 8);
    short8 aFeat1 = *(const short8*)(feat + (size_t)rA * 64 + 32 + quad * 8);

    floatx4 acc[4];
    #pragma unroll
    for (int t = 0; t < 4; ++t) {
        const int n = t * 16 + l16;
        short8 bW0 = *(const short8*)&sWt[n][     quad * 8];
        short8 bW1 = *(const short8*)&sWt[n][32 + quad * 8];
        short8 bL0 = *(const short8*)&sLt[n][     quad * 8];
        short8 bL1 = *(const short8*)&sLt[n][32 + quad * 8];
        floatx4 a = {0.f, 0.f, 0.f, 0.f};
        a = __builtin_amdgcn_mfma_f32_16x16x32_bf16(aAgg0,  bW0, a, 0, 0, 0);
        a = __builtin_amdgcn_mfma_f32_16x16x32_bf16(aAgg1,  bW1, a, 0, 0, 0);
        a = __builtin_amdgcn_mfma_f32_16x16x32_bf16(aFeat0, bL0, a, 0, 0, 0);
        a = __builtin_amdgcn_mfma_f32_16x16x32_bf16(aFeat1, bL1, a, 0, 0, 0);
        acc[t] = a;
    }

    #pragma unroll
    for (int t = 0; t < 4; ++t) {
        const int col = t * 16 + l16;
        const float bh = sbh[col], be = sbe[col];
        #pragma unroll
        for (int i = 0; i < 4; ++i) {
            int lrow = wave * 16 + quad * 4 + i;
            int r = row0 + lrow;
            if (r < N_NODE) {
                float v = acc[t][i] + bh + (sCnt[lrow] > 0 ? be : 0.f);
                outN[(size_t)r * D + col] = v;
            }
        }
    }
}

// ---------------------------------------------------------------------------
extern "C" void kernel_launch(void* const* d_in, const int* in_sizes, int n_in,
                              void* d_out, int out_size, void* d_ws, size_t ws_size,
                              hipStream_t stream)
{
    const float* user_feat = (const float*)d_in[0];
    const float* item_feat = (const float*)d_in[1];
    const int*   rate_src  = (const int*)d_in[2];
    const int*   rate_dst  = (const int*)d_in[3];
    const int*   rev_src   = (const int*)d_in[4];
    const int*   rev_dst   = (const int*)d_in[5];
    const float* W_rate    = (const float*)d_in[6];
    const float* b_rate    = (const float*)d_in[7];
    const float* W_rev     = (const float*)d_in[8];
    const float* b_rev     = (const float*)d_in[9];
    const float* loop_w    = (const float*)d_in[10];
    const float* h_bias    = (const float*)d_in[11];
    float* out = (float*)d_out;

    // workspace layout (~51 MB)
    char* p = (char*)d_ws;
    ushort4* userB = (ushort4*)p; p += (size_t)N_USER * D * 2;                 // 6.4 MB
    ushort4* itemB = (ushort4*)p; p += (size_t)N_ITEM * D * 2;                 // 6.4 MB
    unsigned* gbinI = (unsigned*)p; p += (size_t)NBKT * BCAP * 4;              // 8.0 MB
    unsigned* gbinU = (unsigned*)p; p += (size_t)NBKT * BCAP * 4;              // 8.0 MB
    unsigned short* srtI = (unsigned short*)p; p += (size_t)NBKT * BCAP * 2;   // 4.0 MB
    unsigned short* srtU = (unsigned short*)p; p += (size_t)NBKT * BCAP * 2;   // 4.0 MB
    ushort4* aggI  = (ushort4*)p; p += (size_t)N_NODE * D * 2;                 // 6.4 MB
    ushort4* aggU  = (ushort4*)p; p += (size_t)N_NODE * D * 2;                 // 6.4 MB
    int* offI = (int*)p; p += (size_t)N_NODE * 4;
    int* offU = (int*)p; p += (size_t)N_NODE * 4;
    int* cntI = (int*)p; p += (size_t)N_NODE * 4;
    int* cntU = (int*)p; p += (size_t)N_NODE * 4;
    int* fcur = (int*)p; p += (size_t)(2 * NBKT) * 4;
    (void)ws_size;

    // fcur = per-bucket fill counts, zero-init (1.6 KB)
    hipMemsetAsync(fcur, 0, (size_t)(2 * NBKT) * sizeof(int), stream);

    // 1) merged chunk-sort (blocks [0, 2*NCH), dispatched first)
    //    + cast (blocks [2*NCH, ...), BW-bound, overlaps)
    cast_bin<<<dim3(2 * NCH + 2 * NCAST), 256, 0, stream>>>(
        (const float4*)user_feat, userB, (const float4*)item_feat, itemB,
        rate_src, rate_dst, gbinI,
        rev_src,  rev_dst,  gbinU, fcur);

    // 2) per-coarse-bucket counting sort -> u16 srt + off/cnt
    bucket_sort<<<dim3(NBKT, 2), 256, 0, stream>>>(
        gbinI, srtI, offI, cntI,
        gbinU, srtU, offU, cntU, fcur);

    // 3) raw-feature segment mean (bf16, 8 lanes/node, 16 B loads, unroll-8)
    aggregate_kernel<<<(N_USER + N_ITEM + 31) / 32, 256, 0, stream>>>(
        (const uint4*)itemB, (const uint4*)userB,
        offU, cntU, srtU,
        offI, cntI, srtI,
        (uint4*)aggU, (uint4*)aggI);

    // 4) final dual GEMM via MFMA (merged, fully writes d_out)
    final_gemm<<<dim3((N_NODE + 63) / 64, 2), 256, 0, stream>>>(
        (const unsigned short*)aggU, (const unsigned short*)userB, cntU, W_rev, b_rev,
        (const unsigned short*)aggI, (const unsigned short*)itemB, cntI, W_rate, b_rate,
        loop_w, h_bias, out);

    (void)in_sizes; (void)n_in; (void)out_size;
}